// Round 2
// baseline (212.642 us; speedup 1.0000x reference)
//
#include <hip/hip_runtime.h>
#include <hip/hip_bf16.h>
#include <stdint.h>

#define EMB 1024
#define NB 8
#define SEQ 2048
#define RANK 8
#define KP 72   // padded LDS row stride in bf16 elems (144B, 16B-aligned, conflict-breaking)

typedef __attribute__((ext_vector_type(8))) short bf16x8;
typedef __attribute__((ext_vector_type(4))) float f32x4;
typedef unsigned short u16;
typedef unsigned int u32;

__device__ __forceinline__ u16 f2bf(float f) {
  u32 u = __builtin_bit_cast(u32, f);
  u = (u + 0x7fffu + ((u >> 16) & 1u)) >> 16;   // round-to-nearest-even
  return (u16)u;
}

// ---------------- fold: Weff[m][e] = W[h][e] + 2*sum_r B[h][r]*A[r][e], bf16 out
// grid 192 blocks (m), 256 threads (4 elems each)
__global__ __launch_bounds__(256) void fold_k(
    const float* __restrict__ Wq, const float* __restrict__ Wk, const float* __restrict__ Wv,
    const float* __restrict__ Aq, const float* __restrict__ Bq,
    const float* __restrict__ Ak, const float* __restrict__ Bk,
    const float* __restrict__ Av, const float* __restrict__ Bv,
    u16* __restrict__ weff) {
  int m = blockIdx.x;
  int mat = m >> 6, h = m & 63;
  const float* W = mat == 0 ? Wq : (mat == 1 ? Wk : Wv);
  const float* A = mat == 0 ? Aq : (mat == 1 ? Ak : Av);
  const float* B = mat == 0 ? Bq : (mat == 1 ? Bk : Bv);
  float bb[RANK];
#pragma unroll
  for (int r = 0; r < RANK; r++) bb[r] = 2.0f * B[h * RANK + r];
  int e = threadIdx.x * 4;
  float4 w4 = *(const float4*)(W + h * EMB + e);
  float a0 = w4.x, a1 = w4.y, a2 = w4.z, a3 = w4.w;
#pragma unroll
  for (int r = 0; r < RANK; r++) {
    float4 av = *(const float4*)(A + r * EMB + e);
    a0 += bb[r] * av.x; a1 += bb[r] * av.y; a2 += bb[r] * av.z; a3 += bb[r] * av.w;
  }
  u16* o = weff + (size_t)m * EMB + e;
  o[0] = f2bf(a0); o[1] = f2bf(a1); o[2] = f2bf(a2); o[3] = f2bf(a3);
}

// ---------------- projection GEMM: C[16384,192] = X[16384,1024] * Weff^T
// grid 256 blocks (64 token-rows each), 256 threads = 4 waves (16 rows/wave).
// A from global fp32 (converted in-register), B from global bf16 (L2-resident).
// cols 0-63 -> q [tok][64], 64-127 -> k [tok][64], 128-191 -> v TRANSPOSED [h][tok].
__global__ __launch_bounds__(256) void proj_k(
    const float* __restrict__ X, const u16* __restrict__ weff,
    u16* __restrict__ qws, u16* __restrict__ kws, u16* __restrict__ vws) {
  int w = threadIdx.x >> 6;
  int l = threadIdx.x & 63;
  int l15 = l & 15, lh = l >> 4;
  int koff = lh * 8;
  int row = blockIdx.x * 64 + w * 16 + l15;

  f32x4 acc[12];
  f32x4 zero = {0.f, 0.f, 0.f, 0.f};
#pragma unroll
  for (int t = 0; t < 12; t++) acc[t] = zero;

#pragma unroll 2
  for (int k0 = 0; k0 < EMB; k0 += 32) {
    const float* xp = X + (size_t)row * EMB + k0 + koff;
    float4 xa = *(const float4*)xp;
    float4 xb = *(const float4*)(xp + 4);
    bf16x8 a;
    a[0] = (short)f2bf(xa.x); a[1] = (short)f2bf(xa.y);
    a[2] = (short)f2bf(xa.z); a[3] = (short)f2bf(xa.w);
    a[4] = (short)f2bf(xb.x); a[5] = (short)f2bf(xb.y);
    a[6] = (short)f2bf(xb.z); a[7] = (short)f2bf(xb.w);
#pragma unroll
    for (int t = 0; t < 12; t++) {
      int col = t * 16 + l15;
      bf16x8 b = *(const bf16x8*)(weff + (size_t)col * EMB + k0 + koff);
      acc[t] = __builtin_amdgcn_mfma_f32_16x16x32_bf16(a, b, acc[t], 0, 0, 0);
    }
  }

  int rbase = blockIdx.x * 64 + w * 16 + lh * 4;
#pragma unroll
  for (int t = 0; t < 12; t++) {
    int c = t * 16 + l15;
#pragma unroll
    for (int r = 0; r < 4; r++) {
      int rr = rbase + r;
      u16 v = f2bf(acc[t][r]);
      if (c < 64) {
        qws[(size_t)rr * 64 + c] = v;
      } else if (c < 128) {
        kws[(size_t)rr * 64 + (c - 64)] = v;
      } else {
        int bb = rr >> 11, tok = rr & 2047;
        vws[((size_t)(bb * 64 + (c - 128))) * SEQ + tok] = v;
      }
    }
  }
}

// ---------------- flash attention: grid (32 qtiles, 8 batch), 256 threads = 4 waves.
// Q-tile 64 (16 rows/wave), KV chunk 64. Online softmax in registers.
__global__ __launch_bounds__(256) void attn_k(
    const u16* __restrict__ qws, const u16* __restrict__ kws, const u16* __restrict__ vws,
    const int* __restrict__ mrk, float* __restrict__ out) {
  __shared__ __align__(16) u16 ks[64 * KP];
  __shared__ __align__(16) u16 vt[64 * KP];
  __shared__ __align__(16) u16 ps[4][16 * KP];
  __shared__ float msk[64];

  int b = blockIdx.y;
  int q0 = blockIdx.x * 64;
  int w = threadIdx.x >> 6;
  int l = threadIdx.x & 63;
  int l15 = l & 15, lh = l >> 4;
  int koff = lh * 8;

  const u16* qp = qws + ((size_t)(b * SEQ + q0 + w * 16 + l15)) * 64 + koff;
  bf16x8 aq0 = *(const bf16x8*)qp;
  bf16x8 aq1 = *(const bf16x8*)(qp + 32);

  f32x4 o[4];
  f32x4 zero = {0.f, 0.f, 0.f, 0.f};
#pragma unroll
  for (int t = 0; t < 4; t++) o[t] = zero;
  float mrow[4], lrow[4];
#pragma unroll
  for (int r = 0; r < 4; r++) { mrow[r] = -INFINITY; lrow[r] = 0.f; }

  for (int kc = 0; kc < SEQ / 64; kc++) {
    int kk = kc * 64;
    // ---- stage K and V^T chunks into LDS
    {
      int t = threadIdx.x;
#pragma unroll
      for (int i = 0; i < 4; i++) {
        int idx = t + i * 256;
        int key = idx >> 3, h8 = (idx & 7) * 8;
        *(bf16x8*)&ks[key * KP + h8] =
            *(const bf16x8*)(kws + ((size_t)(b * SEQ + kk + key)) * 64 + h8);
      }
#pragma unroll
      for (int i = 0; i < 4; i++) {
        int idx = t + i * 256;
        int h = idx >> 3, k8 = (idx & 7) * 8;
        *(bf16x8*)&vt[h * KP + k8] =
            *(const bf16x8*)(vws + ((size_t)(b * 64 + h)) * SEQ + kk + k8);
      }
      if (t < 64) msk[t] = (mrk[b * SEQ + kk + t] == 0) ? -INFINITY : 0.0f;
    }
    __syncthreads();

    // ---- scores S = Q K^T  (D rows = lh*4+r, cols = key = nt*16+l15)
    f32x4 sa[4];
#pragma unroll
    for (int nt = 0; nt < 4; nt++) {
      const u16* kb = &ks[(nt * 16 + l15) * KP];
      bf16x8 b0 = *(const bf16x8*)(kb + koff);
      bf16x8 b1 = *(const bf16x8*)(kb + 32 + koff);
      f32x4 s = zero;
      s = __builtin_amdgcn_mfma_f32_16x16x32_bf16(aq0, b0, s, 0, 0, 0);
      s = __builtin_amdgcn_mfma_f32_16x16x32_bf16(aq1, b1, s, 0, 0, 0);
      sa[nt] = s;
    }

    float km[4];
#pragma unroll
    for (int nt = 0; nt < 4; nt++) km[nt] = msk[nt * 16 + l15];

    float pm[4][4];
#pragma unroll
    for (int r = 0; r < 4; r++) {
      float s0 = sa[0][r] * 0.125f + km[0];
      float s1 = sa[1][r] * 0.125f + km[1];
      float s2 = sa[2][r] * 0.125f + km[2];
      float s3 = sa[3][r] * 0.125f + km[3];
      float rm = fmaxf(fmaxf(s0, s1), fmaxf(s2, s3));
      rm = fmaxf(rm, __shfl_xor(rm, 1));
      rm = fmaxf(rm, __shfl_xor(rm, 2));
      rm = fmaxf(rm, __shfl_xor(rm, 4));
      rm = fmaxf(rm, __shfl_xor(rm, 8));
      float nm = fmaxf(mrow[r], rm);
      float nme = (nm == -INFINITY) ? 0.f : nm;    // guards NaN; all-masked rows keep l=0
      float alpha = __expf(mrow[r] - nme);         // 0 when mrow=-inf
      mrow[r] = nm;
      float p0 = __expf(s0 - nme);
      float p1 = __expf(s1 - nme);
      float p2 = __expf(s2 - nme);
      float p3 = __expf(s3 - nme);
      float rs = p0 + p1 + p2 + p3;
      rs += __shfl_xor(rs, 1);
      rs += __shfl_xor(rs, 2);
      rs += __shfl_xor(rs, 4);
      rs += __shfl_xor(rs, 8);
      lrow[r] = lrow[r] * alpha + rs;
      o[0][r] *= alpha; o[1][r] *= alpha; o[2][r] *= alpha; o[3][r] *= alpha;
      pm[0][r] = p0; pm[1][r] = p1; pm[2][r] = p2; pm[3][r] = p3;
    }

    // ---- write P (per-wave region; same-wave LDS ordering, no barrier needed)
    u16* pw = ps[w];
#pragma unroll
    for (int nt = 0; nt < 4; nt++)
#pragma unroll
      for (int r = 0; r < 4; r++)
        pw[(lh * 4 + r) * KP + nt * 16 + l15] = f2bf(pm[nt][r]);

    // ---- PV: O += P V
    bf16x8 ap0 = *(const bf16x8*)&pw[l15 * KP + koff];
    bf16x8 ap1 = *(const bf16x8*)&pw[l15 * KP + 32 + koff];
#pragma unroll
    for (int ht = 0; ht < 4; ht++) {
      const u16* vb = &vt[(ht * 16 + l15) * KP];
      bf16x8 b0 = *(const bf16x8*)(vb + koff);
      bf16x8 b1 = *(const bf16x8*)(vb + 32 + koff);
      o[ht] = __builtin_amdgcn_mfma_f32_16x16x32_bf16(ap0, b0, o[ht], 0, 0, 0);
      o[ht] = __builtin_amdgcn_mfma_f32_16x16x32_bf16(ap1, b1, o[ht], 0, 0, 0);
    }
    __syncthreads();
  }

  // ---- epilogue: normalize, write fp32 (reference output dtype is float32!)
#pragma unroll
  for (int r = 0; r < 4; r++) {
    float inv = lrow[r] > 0.f ? 1.0f / lrow[r] : 0.f;
    int rr = q0 + w * 16 + lh * 4 + r;
#pragma unroll
    for (int ht = 0; ht < 4; ht++) {
      out[((size_t)(b * SEQ + rr)) * 64 + ht * 16 + l15] = o[ht][r] * inv;
    }
  }
}

extern "C" void kernel_launch(void* const* d_in, const int* in_sizes, int n_in,
                              void* d_out, int out_size, void* d_ws, size_t ws_size,
                              hipStream_t stream) {
  const float* X   = (const float*)d_in[0];
  const int*   mrk = (const int*)d_in[1];
  const float* Wq  = (const float*)d_in[2];
  const float* Wk  = (const float*)d_in[3];
  const float* Wv  = (const float*)d_in[4];
  const float* Aq  = (const float*)d_in[5];
  const float* Bq  = (const float*)d_in[6];
  const float* Ak  = (const float*)d_in[7];
  const float* Bk  = (const float*)d_in[8];
  const float* Av  = (const float*)d_in[9];
  const float* Bv  = (const float*)d_in[10];

  // ws layout (bf16): weff 192x1024 @0, q 16384x64 @512KB, k next, v(transposed) next. ~6.5MB.
  u16* weff = (u16*)d_ws;
  u16* qws  = (u16*)((char*)d_ws + (512 << 10));
  u16* kws  = qws + (size_t)16384 * 64;
  u16* vws  = kws + (size_t)16384 * 64;

  fold_k<<<192, 256, 0, stream>>>(Wq, Wk, Wv, Aq, Bq, Ak, Bk, Av, Bv, weff);
  proj_k<<<256, 256, 0, stream>>>(X, weff, qws, kws, vws);
  attn_k<<<dim3(32, 8), 256, 0, stream>>>(qws, kws, vws, mrk, (float*)d_out);
}

// Round 3
// 110.960 us; speedup vs baseline: 1.9164x; 1.9164x over previous
//
#include <hip/hip_runtime.h>
#include <hip/hip_bf16.h>
#include <stdint.h>

#define EMB 1024
#define NB 8
#define SEQ 2048
#define RANK 8
#define KP 72     // padded LDS row stride (bf16 elems)
#define SPLIT 4   // KV splits in flash attention

typedef __attribute__((ext_vector_type(8))) short bf16x8;
typedef __attribute__((ext_vector_type(4))) float f32x4;
typedef unsigned short u16;
typedef unsigned int u32;

__device__ __forceinline__ u16 f2bf(float f) {
  u32 u = __builtin_bit_cast(u32, f);
  u = (u + 0x7fffu + ((u >> 16) & 1u)) >> 16;   // RNE
  return (u16)u;
}

// ---------------- fold: Weff[m][e] = W[h][e] + 2*sum_r B[h][r]*A[r][e]
__global__ __launch_bounds__(256) void fold_k(
    const float* __restrict__ Wq, const float* __restrict__ Wk, const float* __restrict__ Wv,
    const float* __restrict__ Aq, const float* __restrict__ Bq,
    const float* __restrict__ Ak, const float* __restrict__ Bk,
    const float* __restrict__ Av, const float* __restrict__ Bv,
    u16* __restrict__ weff) {
  int m = blockIdx.x;
  int mat = m >> 6, h = m & 63;
  const float* W = mat == 0 ? Wq : (mat == 1 ? Wk : Wv);
  const float* A = mat == 0 ? Aq : (mat == 1 ? Ak : Av);
  const float* B = mat == 0 ? Bq : (mat == 1 ? Bk : Bv);
  float bb[RANK];
#pragma unroll
  for (int r = 0; r < RANK; r++) bb[r] = 2.0f * B[h * RANK + r];
  int e = threadIdx.x * 4;
  float4 w4 = *(const float4*)(W + h * EMB + e);
  float a0 = w4.x, a1 = w4.y, a2 = w4.z, a3 = w4.w;
#pragma unroll
  for (int r = 0; r < RANK; r++) {
    float4 av = *(const float4*)(A + r * EMB + e);
    a0 += bb[r] * av.x; a1 += bb[r] * av.y; a2 += bb[r] * av.z; a3 += bb[r] * av.w;
  }
  u16* o = weff + (size_t)m * EMB + e;
  o[0] = f2bf(a0); o[1] = f2bf(a1); o[2] = f2bf(a2); o[3] = f2bf(a3);
}

// ---------------- projection GEMM: C[16384,192] = X * Weff^T
// grid 512 blocks (32 rows each), 4 waves: 2-way row-split x 2-way col-split.
// 1-deep register prefetch of X (fp32, HBM) and Weff fragments (bf16, L2).
__global__ __launch_bounds__(256) void proj_k(
    const float* __restrict__ X, const u16* __restrict__ weff,
    u16* __restrict__ qws, u16* __restrict__ kws, u16* __restrict__ vws) {
  int w = threadIdx.x >> 6;
  int l = threadIdx.x & 63;
  int l15 = l & 15, lh = l >> 4;
  int koff = lh * 8;
  int rowgrp = w >> 1;      // 0/1: rows
  int colgrp = w & 1;       // 0/1: col tiles 0-5 / 6-11
  int row = blockIdx.x * 32 + rowgrp * 16 + l15;

  const float* xrow = X + (size_t)row * EMB + koff;
  const u16* wp[6];
#pragma unroll
  for (int t = 0; t < 6; t++)
    wp[t] = weff + (size_t)(colgrp * 96 + t * 16 + l15) * EMB + koff;

  f32x4 acc[6];
  f32x4 zero = {0.f, 0.f, 0.f, 0.f};
#pragma unroll
  for (int t = 0; t < 6; t++) acc[t] = zero;

  // prologue
  float4 xa = *(const float4*)(xrow);
  float4 xb = *(const float4*)(xrow + 4);
  bf16x8 wb[6];
#pragma unroll
  for (int t = 0; t < 6; t++) wb[t] = *(const bf16x8*)(wp[t]);

  for (int k0 = 0; k0 < EMB; k0 += 32) {
    int kn = k0 + 32;
    float4 xa_n, xb_n;
    bf16x8 wn[6];
    if (kn < EMB) {                      // issue next-iter loads first
      xa_n = *(const float4*)(xrow + kn);
      xb_n = *(const float4*)(xrow + kn + 4);
#pragma unroll
      for (int t = 0; t < 6; t++) wn[t] = *(const bf16x8*)(wp[t] + kn);
    }
    bf16x8 a;
    a[0] = (short)f2bf(xa.x); a[1] = (short)f2bf(xa.y);
    a[2] = (short)f2bf(xa.z); a[3] = (short)f2bf(xa.w);
    a[4] = (short)f2bf(xb.x); a[5] = (short)f2bf(xb.y);
    a[6] = (short)f2bf(xb.z); a[7] = (short)f2bf(xb.w);
#pragma unroll
    for (int t = 0; t < 6; t++)
      acc[t] = __builtin_amdgcn_mfma_f32_16x16x32_bf16(a, wb[t], acc[t], 0, 0, 0);
    xa = xa_n; xb = xb_n;
#pragma unroll
    for (int t = 0; t < 6; t++) wb[t] = wn[t];
  }

  int rbase = blockIdx.x * 32 + rowgrp * 16 + lh * 4;
#pragma unroll
  for (int t = 0; t < 6; t++) {
    int c = colgrp * 96 + t * 16 + l15;
#pragma unroll
    for (int r = 0; r < 4; r++) {
      int rr = rbase + r;
      u16 v = f2bf(acc[t][r]);
      if (c < 64) {
        qws[(size_t)rr * 64 + c] = v;
      } else if (c < 128) {
        kws[(size_t)rr * 64 + (c - 64)] = v;
      } else {
        int bb = rr >> 11, tok = rr & 2047;
        vws[((size_t)(bb * 64 + (c - 128))) * SEQ + tok] = v;
      }
    }
  }
}

// ---------------- flash attention, KV-split: grid (32 qtiles, 8 batch, SPLIT).
// Each block: 64 q-rows, 512 keys (8 chunks of 64). Writes unnormalized
// partial O (fp32) + per-row m,l to ws.
__global__ __launch_bounds__(256) void attn_k(
    const u16* __restrict__ qws, const u16* __restrict__ kws, const u16* __restrict__ vws,
    const int* __restrict__ mrk,
    float* __restrict__ po, float* __restrict__ pmp, float* __restrict__ plp) {
  __shared__ __align__(16) u16 ks[64 * KP];
  __shared__ __align__(16) u16 vt[64 * KP];
  __shared__ __align__(16) u16 ps[4][16 * KP];
  __shared__ float msk[64];

  int b = blockIdx.y;
  int z = blockIdx.z;
  int q0 = blockIdx.x * 64;
  int w = threadIdx.x >> 6;
  int l = threadIdx.x & 63;
  int l15 = l & 15, lh = l >> 4;
  int koff = lh * 8;

  const u16* qp = qws + ((size_t)(b * SEQ + q0 + w * 16 + l15)) * 64 + koff;
  bf16x8 aq0 = *(const bf16x8*)qp;
  bf16x8 aq1 = *(const bf16x8*)(qp + 32);

  f32x4 o[4];
  f32x4 zero = {0.f, 0.f, 0.f, 0.f};
#pragma unroll
  for (int t = 0; t < 4; t++) o[t] = zero;
  float mrow[4], lrow[4];
#pragma unroll
  for (int r = 0; r < 4; r++) { mrow[r] = -INFINITY; lrow[r] = 0.f; }

  for (int kc = 0; kc < SEQ / 64 / SPLIT; kc++) {
    int kk = z * (SEQ / SPLIT) + kc * 64;
    {
      int t = threadIdx.x;
#pragma unroll
      for (int i = 0; i < 4; i++) {
        int idx = t + i * 256;
        int key = idx >> 3, h8 = (idx & 7) * 8;
        *(bf16x8*)&ks[key * KP + h8] =
            *(const bf16x8*)(kws + ((size_t)(b * SEQ + kk + key)) * 64 + h8);
      }
#pragma unroll
      for (int i = 0; i < 4; i++) {
        int idx = t + i * 256;
        int h = idx >> 3, k8 = (idx & 7) * 8;
        *(bf16x8*)&vt[h * KP + k8] =
            *(const bf16x8*)(vws + ((size_t)(b * 64 + h)) * SEQ + kk + k8);
      }
      if (t < 64) msk[t] = (mrk[b * SEQ + kk + t] == 0) ? -INFINITY : 0.0f;
    }
    __syncthreads();

    // S = Q K^T
    f32x4 sa[4];
#pragma unroll
    for (int nt = 0; nt < 4; nt++) {
      const u16* kb = &ks[(nt * 16 + l15) * KP];
      bf16x8 b0 = *(const bf16x8*)(kb + koff);
      bf16x8 b1 = *(const bf16x8*)(kb + 32 + koff);
      f32x4 s = zero;
      s = __builtin_amdgcn_mfma_f32_16x16x32_bf16(aq0, b0, s, 0, 0, 0);
      s = __builtin_amdgcn_mfma_f32_16x16x32_bf16(aq1, b1, s, 0, 0, 0);
      sa[nt] = s;
    }

    float km[4];
#pragma unroll
    for (int nt = 0; nt < 4; nt++) km[nt] = msk[nt * 16 + l15];

    float pm[4][4];
#pragma unroll
    for (int r = 0; r < 4; r++) {
      float s0 = sa[0][r] * 0.125f + km[0];
      float s1 = sa[1][r] * 0.125f + km[1];
      float s2 = sa[2][r] * 0.125f + km[2];
      float s3 = sa[3][r] * 0.125f + km[3];
      float rm = fmaxf(fmaxf(s0, s1), fmaxf(s2, s3));
      rm = fmaxf(rm, __shfl_xor(rm, 1));
      rm = fmaxf(rm, __shfl_xor(rm, 2));
      rm = fmaxf(rm, __shfl_xor(rm, 4));
      rm = fmaxf(rm, __shfl_xor(rm, 8));
      float nm = fmaxf(mrow[r], rm);
      float nme = (nm == -INFINITY) ? 0.f : nm;
      float alpha = __expf(mrow[r] - nme);
      mrow[r] = nm;
      float p0 = __expf(s0 - nme);
      float p1 = __expf(s1 - nme);
      float p2 = __expf(s2 - nme);
      float p3 = __expf(s3 - nme);
      float rs = p0 + p1 + p2 + p3;
      rs += __shfl_xor(rs, 1);
      rs += __shfl_xor(rs, 2);
      rs += __shfl_xor(rs, 4);
      rs += __shfl_xor(rs, 8);
      lrow[r] = lrow[r] * alpha + rs;
      o[0][r] *= alpha; o[1][r] *= alpha; o[2][r] *= alpha; o[3][r] *= alpha;
      pm[0][r] = p0; pm[1][r] = p1; pm[2][r] = p2; pm[3][r] = p3;
    }

    u16* pw = ps[w];
#pragma unroll
    for (int nt = 0; nt < 4; nt++)
#pragma unroll
      for (int r = 0; r < 4; r++)
        pw[(lh * 4 + r) * KP + nt * 16 + l15] = f2bf(pm[nt][r]);

    bf16x8 ap0 = *(const bf16x8*)&pw[l15 * KP + koff];
    bf16x8 ap1 = *(const bf16x8*)&pw[l15 * KP + 32 + koff];
#pragma unroll
    for (int ht = 0; ht < 4; ht++) {
      const u16* vb = &vt[(ht * 16 + l15) * KP];
      bf16x8 b0 = *(const bf16x8*)(vb + koff);
      bf16x8 b1 = *(const bf16x8*)(vb + 32 + koff);
      o[ht] = __builtin_amdgcn_mfma_f32_16x16x32_bf16(ap0, b0, o[ht], 0, 0, 0);
      o[ht] = __builtin_amdgcn_mfma_f32_16x16x32_bf16(ap1, b1, o[ht], 0, 0, 0);
    }
    __syncthreads();
  }

  // ---- write partials (unnormalized O, running m, l)
#pragma unroll
  for (int r = 0; r < 4; r++) {
    int rr = q0 + w * 16 + lh * 4 + r;
    size_t grow = (size_t)b * SEQ + rr;
    float* pob = po + ((size_t)z * NB * SEQ + grow) * 64;
#pragma unroll
    for (int ht = 0; ht < 4; ht++) pob[ht * 16 + l15] = o[ht][r];
    if (l15 == 0) {
      pmp[(size_t)z * NB * SEQ + grow] = mrow[r];
      plp[(size_t)z * NB * SEQ + grow] = lrow[r];
    }
  }
}

// ---------------- merge SPLIT partials -> fp32 out
// grid 512 blocks, 256 threads: 32 rows/block, 8 threads/row (8 cols each).
__global__ __launch_bounds__(256) void merge_k(
    const float* __restrict__ po, const float* __restrict__ pmp,
    const float* __restrict__ plp, float* __restrict__ out) {
  int tid = threadIdx.x;
  int row = blockIdx.x * 32 + (tid >> 3);      // global row in [0, NB*SEQ)
  int c8 = (tid & 7) * 8;
  const int RT = NB * SEQ;

  float m[SPLIT], lv[SPLIT];
  float M = -INFINITY;
#pragma unroll
  for (int s = 0; s < SPLIT; s++) {
    m[s] = pmp[(size_t)s * RT + row];
    lv[s] = plp[(size_t)s * RT + row];
    M = fmaxf(M, m[s]);
  }
  float o8[8];
#pragma unroll
  for (int j = 0; j < 8; j++) o8[j] = 0.f;
  float L = 0.f;
  if (M != -INFINITY) {
#pragma unroll
    for (int s = 0; s < SPLIT; s++) {
      float ws = __expf(m[s] - M);             // 0 for m[s] = -inf
      L += ws * lv[s];
      const float* p = po + ((size_t)s * RT + row) * 64 + c8;
#pragma unroll
      for (int j = 0; j < 8; j++) o8[j] += ws * p[j];
    }
  }
  float inv = (L > 0.f) ? 1.0f / L : 0.f;
  float* op = out + (size_t)row * 64 + c8;
#pragma unroll
  for (int j = 0; j < 8; j++) op[j] = o8[j] * inv;
}

extern "C" void kernel_launch(void* const* d_in, const int* in_sizes, int n_in,
                              void* d_out, int out_size, void* d_ws, size_t ws_size,
                              hipStream_t stream) {
  const float* X   = (const float*)d_in[0];
  const int*   mrk = (const int*)d_in[1];
  const float* Wq  = (const float*)d_in[2];
  const float* Wk  = (const float*)d_in[3];
  const float* Wv  = (const float*)d_in[4];
  const float* Aq  = (const float*)d_in[5];
  const float* Bq  = (const float*)d_in[6];
  const float* Ak  = (const float*)d_in[7];
  const float* Bk  = (const float*)d_in[8];
  const float* Av  = (const float*)d_in[9];
  const float* Bv  = (const float*)d_in[10];

  // ws layout: weff bf16 @0 (384KB), q/k/v bf16 @512KB (2MB each),
  // po fp32 @6.5MB (16MB), pm/pl fp32 after (256KB each). Total ~23MB.
  u16* weff = (u16*)d_ws;
  u16* qws  = (u16*)((char*)d_ws + (512 << 10));
  u16* kws  = qws + (size_t)16384 * 64;
  u16* vws  = kws + (size_t)16384 * 64;
  float* po  = (float*)((char*)d_ws + ((size_t)6656 << 10));
  float* pmp = po + (size_t)SPLIT * 16384 * 64;
  float* plp = pmp + (size_t)SPLIT * 16384;

  fold_k<<<192, 256, 0, stream>>>(Wq, Wk, Wv, Aq, Bq, Ak, Bk, Av, Bv, weff);
  proj_k<<<512, 256, 0, stream>>>(X, weff, qws, kws, vws);
  attn_k<<<dim3(32, 8, SPLIT), 256, 0, stream>>>(qws, kws, vws, mrk, po, pmp, plp);
  merge_k<<<512, 256, 0, stream>>>(po, pmp, plp, (float*)d_out);
}

// Round 4
// 99.186 us; speedup vs baseline: 2.1439x; 1.1187x over previous
//
#include <hip/hip_runtime.h>
#include <hip/hip_bf16.h>
#include <stdint.h>

#define EMB 1024
#define NB 8
#define SEQ 2048
#define RANK 8
#define KP 72     // padded LDS row stride (bf16 elems)
#define SPLIT 4   // KV splits in flash attention

typedef __attribute__((ext_vector_type(8))) short bf16x8;
typedef __attribute__((ext_vector_type(4))) float f32x4;
typedef unsigned short u16;
typedef unsigned int u32;

__device__ __forceinline__ u16 f2bf(float f) {
  u32 u = __builtin_bit_cast(u32, f);
  u = (u + 0x7fffu + ((u >> 16) & 1u)) >> 16;   // RNE
  return (u16)u;
}
__device__ __forceinline__ u32 pack2bf(float lo, float hi) {
  return (u32)f2bf(lo) | ((u32)f2bf(hi) << 16);
}

// ---------------- fold: Weff[m][e] = W[h][e] + 2*sum_r B[h][r]*A[r][e]
__global__ __launch_bounds__(256) void fold_k(
    const float* __restrict__ Wq, const float* __restrict__ Wk, const float* __restrict__ Wv,
    const float* __restrict__ Aq, const float* __restrict__ Bq,
    const float* __restrict__ Ak, const float* __restrict__ Bk,
    const float* __restrict__ Av, const float* __restrict__ Bv,
    u16* __restrict__ weff) {
  int m = blockIdx.x;
  int mat = m >> 6, h = m & 63;
  const float* W = mat == 0 ? Wq : (mat == 1 ? Wk : Wv);
  const float* A = mat == 0 ? Aq : (mat == 1 ? Ak : Av);
  const float* B = mat == 0 ? Bq : (mat == 1 ? Bk : Bv);
  float bb[RANK];
#pragma unroll
  for (int r = 0; r < RANK; r++) bb[r] = 2.0f * B[h * RANK + r];
  int e = threadIdx.x * 4;
  float4 w4 = *(const float4*)(W + h * EMB + e);
  float a0 = w4.x, a1 = w4.y, a2 = w4.z, a3 = w4.w;
#pragma unroll
  for (int r = 0; r < RANK; r++) {
    float4 av = *(const float4*)(A + r * EMB + e);
    a0 += bb[r] * av.x; a1 += bb[r] * av.y; a2 += bb[r] * av.z; a3 += bb[r] * av.w;
  }
  u16* o = weff + (size_t)m * EMB + e;
  o[0] = f2bf(a0); o[1] = f2bf(a1); o[2] = f2bf(a2); o[3] = f2bf(a3);
}

// ---------------- projection GEMM: C[16384,192] = X * Weff^T
// 1024 blocks x 4 waves. Block = 16 rows; waves col-split 4-way (48 cols each).
// X staged per block into LDS as bf16 (converted once, shared by all waves),
// double-buffered, issue-early (1-iter-ahead) global loads. W from L2 with
// 1-deep register prefetch.
__global__ __launch_bounds__(256, 4) void proj_k(
    const float* __restrict__ X, const u16* __restrict__ weff,
    u16* __restrict__ qws, u16* __restrict__ kws, u16* __restrict__ vws) {
  __shared__ __align__(16) u16 xs[2][16 * KP];

  int w = threadIdx.x >> 6;
  int l = threadIdx.x & 63;
  int l15 = l & 15, lh = l >> 4;
  int rbase = blockIdx.x * 16;

  // staging coords: thread t covers X[rbase + (t>>4)][ (t&15)*4 .. +4 ) per k-step
  int srow = threadIdx.x >> 4, sseg = threadIdx.x & 15;
  const float* xsrc = X + (size_t)(rbase + srow) * EMB + sseg * 4;
  u16* xdst = &xs[0][0] + srow * KP + sseg * 4;   // + buf*16*KP

  // W fragment pointers: tile t -> col w*48 + t*16 + l15
  const u16* wptr[3];
#pragma unroll
  for (int t = 0; t < 3; t++)
    wptr[t] = weff + (size_t)(w * 48 + t * 16 + l15) * EMB + lh * 8;

  f32x4 acc[3];
  f32x4 zero = {0.f, 0.f, 0.f, 0.f};
#pragma unroll
  for (int t = 0; t < 3; t++) acc[t] = zero;

  bf16x8 wc[3][2], wn[3][2];
  float4 xr[2];

  // ---- prologue: stage X(0) into buf0, load W(0), issue X(64)/W(64)
  {
    float4 x0 = *(const float4*)(xsrc);
    *(uint2*)(xdst) = make_uint2(pack2bf(x0.x, x0.y), pack2bf(x0.z, x0.w));
#pragma unroll
    for (int t = 0; t < 3; t++) {
      wc[t][0] = *(const bf16x8*)(wptr[t]);
      wc[t][1] = *(const bf16x8*)(wptr[t] + 32);
    }
    xr[1] = *(const float4*)(xsrc + 64);
#pragma unroll
    for (int t = 0; t < 3; t++) {
      wn[t][0] = *(const bf16x8*)(wptr[t] + 64);
      wn[t][1] = *(const bf16x8*)(wptr[t] + 96);
    }
  }
  __syncthreads();

  for (int kk = 0; kk < EMB; kk += 128) {
#pragma unroll
    for (int half = 0; half < 2; half++) {
      int k0 = kk + half * 64;
      int cur = (k0 >> 6) & 1;
      // 1) issue X(k0+128) early into the free slot
      if (k0 + 128 < EMB) xr[half] = *(const float4*)(xsrc + k0 + 128);
      // 2) compute current tile
      const u16* xc = &xs[cur][0];
#pragma unroll
      for (int k32 = 0; k32 < 2; k32++) {
        bf16x8 a = *(const bf16x8*)(xc + l15 * KP + k32 * 32 + lh * 8);
#pragma unroll
        for (int t = 0; t < 3; t++)
          acc[t] = __builtin_amdgcn_mfma_f32_16x16x32_bf16(a, wc[t][k32], acc[t], 0, 0, 0);
      }
      if (k0 + 64 < EMB) {
        // 3) stage X(k0+64) (issued one iter ago) into other buffer
        float4 xa = xr[half ^ 1];
        *(uint2*)(xdst + (cur ^ 1) * 16 * KP) =
            make_uint2(pack2bf(xa.x, xa.y), pack2bf(xa.z, xa.w));
        // 4) roll W prefetch
#pragma unroll
        for (int t = 0; t < 3; t++) { wc[t][0] = wn[t][0]; wc[t][1] = wn[t][1]; }
        if (k0 + 128 < EMB) {
#pragma unroll
          for (int t = 0; t < 3; t++) {
            wn[t][0] = *(const bf16x8*)(wptr[t] + k0 + 128);
            wn[t][1] = *(const bf16x8*)(wptr[t] + k0 + 160);
          }
        }
        // 5) barrier: buf[cur^1] now staged for next iter
        __syncthreads();
      }
    }
  }

  // ---- epilogue: scatter to q / k / v^T (bf16)
#pragma unroll
  for (int t = 0; t < 3; t++) {
    int c = w * 48 + t * 16 + l15;
#pragma unroll
    for (int r = 0; r < 4; r++) {
      int rr = rbase + lh * 4 + r;
      u16 v = f2bf(acc[t][r]);
      if (c < 64) {
        qws[(size_t)rr * 64 + c] = v;
      } else if (c < 128) {
        kws[(size_t)rr * 64 + (c - 64)] = v;
      } else {
        int bb = rr >> 11, tok = rr & 2047;
        vws[((size_t)(bb * 64 + (c - 128))) * SEQ + tok] = v;
      }
    }
  }
}

// ---------------- flash attention, KV-split: grid (32 qtiles, 8 batch, SPLIT).
__global__ __launch_bounds__(256) void attn_k(
    const u16* __restrict__ qws, const u16* __restrict__ kws, const u16* __restrict__ vws,
    const int* __restrict__ mrk,
    float* __restrict__ po, float* __restrict__ pmp, float* __restrict__ plp) {
  __shared__ __align__(16) u16 ks[64 * KP];
  __shared__ __align__(16) u16 vt[64 * KP];
  __shared__ __align__(16) u16 ps[4][16 * KP];
  __shared__ float msk[64];

  int b = blockIdx.y;
  int z = blockIdx.z;
  int q0 = blockIdx.x * 64;
  int w = threadIdx.x >> 6;
  int l = threadIdx.x & 63;
  int l15 = l & 15, lh = l >> 4;
  int koff = lh * 8;

  const u16* qp = qws + ((size_t)(b * SEQ + q0 + w * 16 + l15)) * 64 + koff;
  bf16x8 aq0 = *(const bf16x8*)qp;
  bf16x8 aq1 = *(const bf16x8*)(qp + 32);

  f32x4 o[4];
  f32x4 zero = {0.f, 0.f, 0.f, 0.f};
#pragma unroll
  for (int t = 0; t < 4; t++) o[t] = zero;
  float mrow[4], lrow[4];
#pragma unroll
  for (int r = 0; r < 4; r++) { mrow[r] = -INFINITY; lrow[r] = 0.f; }

  for (int kc = 0; kc < SEQ / 64 / SPLIT; kc++) {
    int kk = z * (SEQ / SPLIT) + kc * 64;
    {
      int t = threadIdx.x;
#pragma unroll
      for (int i = 0; i < 4; i++) {
        int idx = t + i * 256;
        int key = idx >> 3, h8 = (idx & 7) * 8;
        *(bf16x8*)&ks[key * KP + h8] =
            *(const bf16x8*)(kws + ((size_t)(b * SEQ + kk + key)) * 64 + h8);
      }
#pragma unroll
      for (int i = 0; i < 4; i++) {
        int idx = t + i * 256;
        int h = idx >> 3, k8 = (idx & 7) * 8;
        *(bf16x8*)&vt[h * KP + k8] =
            *(const bf16x8*)(vws + ((size_t)(b * 64 + h)) * SEQ + kk + k8);
      }
      if (t < 64) msk[t] = (mrk[b * SEQ + kk + t] == 0) ? -INFINITY : 0.0f;
    }
    __syncthreads();

    // S = Q K^T
    f32x4 sa[4];
#pragma unroll
    for (int nt = 0; nt < 4; nt++) {
      const u16* kb = &ks[(nt * 16 + l15) * KP];
      bf16x8 b0 = *(const bf16x8*)(kb + koff);
      bf16x8 b1 = *(const bf16x8*)(kb + 32 + koff);
      f32x4 s = zero;
      s = __builtin_amdgcn_mfma_f32_16x16x32_bf16(aq0, b0, s, 0, 0, 0);
      s = __builtin_amdgcn_mfma_f32_16x16x32_bf16(aq1, b1, s, 0, 0, 0);
      sa[nt] = s;
    }

    float km[4];
#pragma unroll
    for (int nt = 0; nt < 4; nt++) km[nt] = msk[nt * 16 + l15];

    float pm[4][4];
#pragma unroll
    for (int r = 0; r < 4; r++) {
      float s0 = sa[0][r] * 0.125f + km[0];
      float s1 = sa[1][r] * 0.125f + km[1];
      float s2 = sa[2][r] * 0.125f + km[2];
      float s3 = sa[3][r] * 0.125f + km[3];
      float rm = fmaxf(fmaxf(s0, s1), fmaxf(s2, s3));
      rm = fmaxf(rm, __shfl_xor(rm, 1));
      rm = fmaxf(rm, __shfl_xor(rm, 2));
      rm = fmaxf(rm, __shfl_xor(rm, 4));
      rm = fmaxf(rm, __shfl_xor(rm, 8));
      float nm = fmaxf(mrow[r], rm);
      float nme = (nm == -INFINITY) ? 0.f : nm;
      float alpha = __expf(mrow[r] - nme);
      mrow[r] = nm;
      float p0 = __expf(s0 - nme);
      float p1 = __expf(s1 - nme);
      float p2 = __expf(s2 - nme);
      float p3 = __expf(s3 - nme);
      float rs = p0 + p1 + p2 + p3;
      rs += __shfl_xor(rs, 1);
      rs += __shfl_xor(rs, 2);
      rs += __shfl_xor(rs, 4);
      rs += __shfl_xor(rs, 8);
      lrow[r] = lrow[r] * alpha + rs;
      o[0][r] *= alpha; o[1][r] *= alpha; o[2][r] *= alpha; o[3][r] *= alpha;
      pm[0][r] = p0; pm[1][r] = p1; pm[2][r] = p2; pm[3][r] = p3;
    }

    u16* pw = ps[w];
#pragma unroll
    for (int nt = 0; nt < 4; nt++)
#pragma unroll
      for (int r = 0; r < 4; r++)
        pw[(lh * 4 + r) * KP + nt * 16 + l15] = f2bf(pm[nt][r]);

    bf16x8 ap0 = *(const bf16x8*)&pw[l15 * KP + koff];
    bf16x8 ap1 = *(const bf16x8*)&pw[l15 * KP + 32 + koff];
#pragma unroll
    for (int ht = 0; ht < 4; ht++) {
      const u16* vb = &vt[(ht * 16 + l15) * KP];
      bf16x8 b0 = *(const bf16x8*)(vb + koff);
      bf16x8 b1 = *(const bf16x8*)(vb + 32 + koff);
      o[ht] = __builtin_amdgcn_mfma_f32_16x16x32_bf16(ap0, b0, o[ht], 0, 0, 0);
      o[ht] = __builtin_amdgcn_mfma_f32_16x16x32_bf16(ap1, b1, o[ht], 0, 0, 0);
    }
    __syncthreads();
  }

  // ---- write partials (unnormalized O, running m, l)
#pragma unroll
  for (int r = 0; r < 4; r++) {
    int rr = q0 + w * 16 + lh * 4 + r;
    size_t grow = (size_t)b * SEQ + rr;
    float* pob = po + ((size_t)z * NB * SEQ + grow) * 64;
#pragma unroll
    for (int ht = 0; ht < 4; ht++) pob[ht * 16 + l15] = o[ht][r];
    if (l15 == 0) {
      pmp[(size_t)z * NB * SEQ + grow] = mrow[r];
      plp[(size_t)z * NB * SEQ + grow] = lrow[r];
    }
  }
}

// ---------------- merge SPLIT partials -> fp32 out
__global__ __launch_bounds__(256) void merge_k(
    const float* __restrict__ po, const float* __restrict__ pmp,
    const float* __restrict__ plp, float* __restrict__ out) {
  int tid = threadIdx.x;
  int row = blockIdx.x * 32 + (tid >> 3);
  int c8 = (tid & 7) * 8;
  const int RT = NB * SEQ;

  float m[SPLIT], lv[SPLIT];
  float M = -INFINITY;
#pragma unroll
  for (int s = 0; s < SPLIT; s++) {
    m[s] = pmp[(size_t)s * RT + row];
    lv[s] = plp[(size_t)s * RT + row];
    M = fmaxf(M, m[s]);
  }
  float o8[8];
#pragma unroll
  for (int j = 0; j < 8; j++) o8[j] = 0.f;
  float L = 0.f;
  if (M != -INFINITY) {
#pragma unroll
    for (int s = 0; s < SPLIT; s++) {
      float ws = __expf(m[s] - M);
      L += ws * lv[s];
      const float* p = po + ((size_t)s * RT + row) * 64 + c8;
#pragma unroll
      for (int j = 0; j < 8; j++) o8[j] += ws * p[j];
    }
  }
  float inv = (L > 0.f) ? 1.0f / L : 0.f;
  float* op = out + (size_t)row * 64 + c8;
#pragma unroll
  for (int j = 0; j < 8; j++) op[j] = o8[j] * inv;
}

extern "C" void kernel_launch(void* const* d_in, const int* in_sizes, int n_in,
                              void* d_out, int out_size, void* d_ws, size_t ws_size,
                              hipStream_t stream) {
  const float* X   = (const float*)d_in[0];
  const int*   mrk = (const int*)d_in[1];
  const float* Wq  = (const float*)d_in[2];
  const float* Wk  = (const float*)d_in[3];
  const float* Wv  = (const float*)d_in[4];
  const float* Aq  = (const float*)d_in[5];
  const float* Bq  = (const float*)d_in[6];
  const float* Ak  = (const float*)d_in[7];
  const float* Bk  = (const float*)d_in[8];
  const float* Av  = (const float*)d_in[9];
  const float* Bv  = (const float*)d_in[10];

  u16* weff = (u16*)d_ws;
  u16* qws  = (u16*)((char*)d_ws + (512 << 10));
  u16* kws  = qws + (size_t)16384 * 64;
  u16* vws  = kws + (size_t)16384 * 64;
  float* po  = (float*)((char*)d_ws + ((size_t)6656 << 10));
  float* pmp = po + (size_t)SPLIT * 16384 * 64;
  float* plp = pmp + (size_t)SPLIT * 16384;

  fold_k<<<192, 256, 0, stream>>>(Wq, Wk, Wv, Aq, Bq, Ak, Bk, Av, Bv, weff);
  proj_k<<<1024, 256, 0, stream>>>(X, weff, qws, kws, vws);
  attn_k<<<dim3(32, 8, SPLIT), 256, 0, stream>>>(qws, kws, vws, mrk, po, pmp, plp);
  merge_k<<<512, 256, 0, stream>>>(po, pmp, plp, (float*)d_out);
}

// Round 5
// 84.846 us; speedup vs baseline: 2.5062x; 1.1690x over previous
//
#include <hip/hip_runtime.h>
#include <hip/hip_bf16.h>
#include <stdint.h>

#define EMB 1024
#define NB 8
#define SEQ 2048
#define RANK 8
#define KP 72      // attn LDS row stride (bf16 elems)
#define SPLIT 4    // KV splits in flash attention
#define PROWS 32   // proj rows per block

typedef __attribute__((ext_vector_type(8))) short bf16x8;
typedef __attribute__((ext_vector_type(4))) float f32x4;
typedef unsigned short u16;
typedef unsigned int u32;

__device__ __forceinline__ u16 f2bf(float f) {
  u32 u = __builtin_bit_cast(u32, f);
  u = (u + 0x7fffu + ((u >> 16) & 1u)) >> 16;   // RNE
  return (u16)u;
}
__device__ __forceinline__ u32 pack2bf(float lo, float hi) {
  return (u32)f2bf(lo) | ((u32)f2bf(hi) << 16);
}

// ---------------- fold: Weff[m][e] = W[h][e] + 2*sum_r B[h][r]*A[r][e]
__global__ __launch_bounds__(256) void fold_k(
    const float* __restrict__ Wq, const float* __restrict__ Wk, const float* __restrict__ Wv,
    const float* __restrict__ Aq, const float* __restrict__ Bq,
    const float* __restrict__ Ak, const float* __restrict__ Bk,
    const float* __restrict__ Av, const float* __restrict__ Bv,
    u16* __restrict__ weff) {
  int m = blockIdx.x;
  int mat = m >> 6, h = m & 63;
  const float* W = mat == 0 ? Wq : (mat == 1 ? Wk : Wv);
  const float* A = mat == 0 ? Aq : (mat == 1 ? Ak : Av);
  const float* B = mat == 0 ? Bq : (mat == 1 ? Bk : Bv);
  float bb[RANK];
#pragma unroll
  for (int r = 0; r < RANK; r++) bb[r] = 2.0f * B[h * RANK + r];
  int e = threadIdx.x * 4;
  float4 w4 = *(const float4*)(W + h * EMB + e);
  float a0 = w4.x, a1 = w4.y, a2 = w4.z, a3 = w4.w;
#pragma unroll
  for (int r = 0; r < RANK; r++) {
    float4 av = *(const float4*)(A + r * EMB + e);
    a0 += bb[r] * av.x; a1 += bb[r] * av.y; a2 += bb[r] * av.z; a3 += bb[r] * av.w;
  }
  u16* o = weff + (size_t)m * EMB + e;
  o[0] = f2bf(a0); o[1] = f2bf(a1); o[2] = f2bf(a2); o[3] = f2bf(a3);
}

// ---------------- projection GEMM: C[16384,192] = X * Weff^T
// 512 blocks x 4 waves, 32 rows/block. X burst-staged (2x16 independent
// float4 loads/thread) into 64KB XOR-swizzled bf16 LDS; ONE barrier; then a
// barrier-free K loop: waves col-split 4-way, W register-prefetched from L2.
__global__ __launch_bounds__(256) void proj_k(
    const float* __restrict__ X, const u16* __restrict__ weff,
    u16* __restrict__ qws, u16* __restrict__ kws, u16* __restrict__ vws) {
  __shared__ __align__(16) u16 xs[PROWS * EMB];   // 64KB, swz: byte ^= (row&7)<<4

  int t = threadIdx.x;
  int w = t >> 6;
  int l = t & 63;
  int l15 = l & 15, lh = l >> 4;
  int rbase = blockIdx.x * PROWS;

  // ---- stage X: thread t covers bytes [t*16, t*16+16) of each row
  const float* xsrc = X + (size_t)rbase * EMB + t * 4;
  {
    float4 xr[16];
#pragma unroll
    for (int h = 0; h < 2; h++) {
#pragma unroll
      for (int i = 0; i < 16; i++)
        xr[i] = *(const float4*)(xsrc + (size_t)(h * 16 + i) * EMB);
#pragma unroll
      for (int i = 0; i < 16; i++) {
        int row = h * 16 + i;
        u32 boff = (u32)(row * 2048 + t * 8) ^ (u32)((row & 7) << 4);
        *(uint2*)((char*)xs + boff) =
            make_uint2(pack2bf(xr[i].x, xr[i].y), pack2bf(xr[i].z, xr[i].w));
      }
    }
  }
  __syncthreads();

  // ---- compute: 2 row-tiles x 3 col-tiles per wave
  const u16* wptr[3];
#pragma unroll
  for (int tt = 0; tt < 3; tt++)
    wptr[tt] = weff + (size_t)(w * 48 + tt * 16 + l15) * EMB + lh * 8;

  f32x4 acc[2][3];
  f32x4 zero = {0.f, 0.f, 0.f, 0.f};
#pragma unroll
  for (int rt = 0; rt < 2; rt++)
#pragma unroll
    for (int tt = 0; tt < 3; tt++) acc[rt][tt] = zero;

  int aconst0 = (0 * 16 + l15) * 2048 + lh * 16;
  int aconst1 = (1 * 16 + l15) * 2048 + lh * 16;
  int swz = (l15 & 7) << 4;

  bf16x8 wc[2][3], wn[2][3], w2[2][3];
  // prologue: W(0) and W(64)
#pragma unroll
  for (int h = 0; h < 2; h++)
#pragma unroll
    for (int tt = 0; tt < 3; tt++) {
      wc[h][tt] = *(const bf16x8*)(wptr[tt] + h * 32);
      wn[h][tt] = *(const bf16x8*)(wptr[tt] + 64 + h * 32);
    }

  for (int k0 = 0; k0 < EMB; k0 += 64) {
    int kp = (k0 + 128 < EMB) ? (k0 + 128) : 0;   // clamped, branch-free tail
    // issue next-next W loads early (L2, ~200cy to cover)
#pragma unroll
    for (int h = 0; h < 2; h++)
#pragma unroll
      for (int tt = 0; tt < 3; tt++)
        w2[h][tt] = *(const bf16x8*)(wptr[tt] + kp + h * 32);
    // compute current 64-k with wc
#pragma unroll
    for (int h = 0; h < 2; h++) {
      int k2 = (k0 + h * 32) * 2;
      bf16x8 a0 = *(const bf16x8*)((const char*)xs + ((aconst0 + k2) ^ swz));
      bf16x8 a1 = *(const bf16x8*)((const char*)xs + ((aconst1 + k2) ^ swz));
#pragma unroll
      for (int tt = 0; tt < 3; tt++) {
        acc[0][tt] = __builtin_amdgcn_mfma_f32_16x16x32_bf16(a0, wc[h][tt], acc[0][tt], 0, 0, 0);
        acc[1][tt] = __builtin_amdgcn_mfma_f32_16x16x32_bf16(a1, wc[h][tt], acc[1][tt], 0, 0, 0);
      }
    }
    // roll prefetch
#pragma unroll
    for (int h = 0; h < 2; h++)
#pragma unroll
      for (int tt = 0; tt < 3; tt++) { wc[h][tt] = wn[h][tt]; wn[h][tt] = w2[h][tt]; }
  }

  // ---- epilogue: scatter to q / k / v^T (bf16)
#pragma unroll
  for (int rt = 0; rt < 2; rt++)
#pragma unroll
    for (int tt = 0; tt < 3; tt++) {
      int c = w * 48 + tt * 16 + l15;
#pragma unroll
      for (int r = 0; r < 4; r++) {
        int rr = rbase + rt * 16 + lh * 4 + r;
        u16 v = f2bf(acc[rt][tt][r]);
        if (c < 64) {
          qws[(size_t)rr * 64 + c] = v;
        } else if (c < 128) {
          kws[(size_t)rr * 64 + (c - 64)] = v;
        } else {
          int bb = rr >> 11, tok = rr & 2047;
          vws[((size_t)(bb * 64 + (c - 128))) * SEQ + tok] = v;
        }
      }
    }
}

// ---------------- flash attention, KV-split: grid (32 qtiles, 8 batch, SPLIT).
__global__ __launch_bounds__(256) void attn_k(
    const u16* __restrict__ qws, const u16* __restrict__ kws, const u16* __restrict__ vws,
    const int* __restrict__ mrk,
    float* __restrict__ po, float* __restrict__ pmp, float* __restrict__ plp) {
  __shared__ __align__(16) u16 ks[64 * KP];
  __shared__ __align__(16) u16 vt[64 * KP];
  __shared__ __align__(16) u16 ps[4][16 * KP];
  __shared__ float msk[64];

  int b = blockIdx.y;
  int z = blockIdx.z;
  int q0 = blockIdx.x * 64;
  int w = threadIdx.x >> 6;
  int l = threadIdx.x & 63;
  int l15 = l & 15, lh = l >> 4;
  int koff = lh * 8;

  const u16* qp = qws + ((size_t)(b * SEQ + q0 + w * 16 + l15)) * 64 + koff;
  bf16x8 aq0 = *(const bf16x8*)qp;
  bf16x8 aq1 = *(const bf16x8*)(qp + 32);

  f32x4 o[4];
  f32x4 zero = {0.f, 0.f, 0.f, 0.f};
#pragma unroll
  for (int t = 0; t < 4; t++) o[t] = zero;
  float mrow[4], lrow[4];
#pragma unroll
  for (int r = 0; r < 4; r++) { mrow[r] = -INFINITY; lrow[r] = 0.f; }

  for (int kc = 0; kc < SEQ / 64 / SPLIT; kc++) {
    int kk = z * (SEQ / SPLIT) + kc * 64;
    {
      int t = threadIdx.x;
#pragma unroll
      for (int i = 0; i < 4; i++) {
        int idx = t + i * 256;
        int key = idx >> 3, h8 = (idx & 7) * 8;
        *(bf16x8*)&ks[key * KP + h8] =
            *(const bf16x8*)(kws + ((size_t)(b * SEQ + kk + key)) * 64 + h8);
      }
#pragma unroll
      for (int i = 0; i < 4; i++) {
        int idx = t + i * 256;
        int h = idx >> 3, k8 = (idx & 7) * 8;
        *(bf16x8*)&vt[h * KP + k8] =
            *(const bf16x8*)(vws + ((size_t)(b * 64 + h)) * SEQ + kk + k8);
      }
      if (t < 64) msk[t] = (mrk[b * SEQ + kk + t] == 0) ? -INFINITY : 0.0f;
    }
    __syncthreads();

    // S = Q K^T
    f32x4 sa[4];
#pragma unroll
    for (int nt = 0; nt < 4; nt++) {
      const u16* kb = &ks[(nt * 16 + l15) * KP];
      bf16x8 b0 = *(const bf16x8*)(kb + koff);
      bf16x8 b1 = *(const bf16x8*)(kb + 32 + koff);
      f32x4 s = zero;
      s = __builtin_amdgcn_mfma_f32_16x16x32_bf16(aq0, b0, s, 0, 0, 0);
      s = __builtin_amdgcn_mfma_f32_16x16x32_bf16(aq1, b1, s, 0, 0, 0);
      sa[nt] = s;
    }

    float km[4];
#pragma unroll
    for (int nt = 0; nt < 4; nt++) km[nt] = msk[nt * 16 + l15];

    float pm[4][4];
#pragma unroll
    for (int r = 0; r < 4; r++) {
      float s0 = sa[0][r] * 0.125f + km[0];
      float s1 = sa[1][r] * 0.125f + km[1];
      float s2 = sa[2][r] * 0.125f + km[2];
      float s3 = sa[3][r] * 0.125f + km[3];
      float rm = fmaxf(fmaxf(s0, s1), fmaxf(s2, s3));
      rm = fmaxf(rm, __shfl_xor(rm, 1));
      rm = fmaxf(rm, __shfl_xor(rm, 2));
      rm = fmaxf(rm, __shfl_xor(rm, 4));
      rm = fmaxf(rm, __shfl_xor(rm, 8));
      float nm = fmaxf(mrow[r], rm);
      float nme = (nm == -INFINITY) ? 0.f : nm;
      float alpha = __expf(mrow[r] - nme);
      mrow[r] = nm;
      float p0 = __expf(s0 - nme);
      float p1 = __expf(s1 - nme);
      float p2 = __expf(s2 - nme);
      float p3 = __expf(s3 - nme);
      float rs = p0 + p1 + p2 + p3;
      rs += __shfl_xor(rs, 1);
      rs += __shfl_xor(rs, 2);
      rs += __shfl_xor(rs, 4);
      rs += __shfl_xor(rs, 8);
      lrow[r] = lrow[r] * alpha + rs;
      o[0][r] *= alpha; o[1][r] *= alpha; o[2][r] *= alpha; o[3][r] *= alpha;
      pm[0][r] = p0; pm[1][r] = p1; pm[2][r] = p2; pm[3][r] = p3;
    }

    u16* pw = ps[w];
#pragma unroll
    for (int nt = 0; nt < 4; nt++)
#pragma unroll
      for (int r = 0; r < 4; r++)
        pw[(lh * 4 + r) * KP + nt * 16 + l15] = f2bf(pm[nt][r]);

    bf16x8 ap0 = *(const bf16x8*)&pw[l15 * KP + koff];
    bf16x8 ap1 = *(const bf16x8*)&pw[l15 * KP + 32 + koff];
#pragma unroll
    for (int ht = 0; ht < 4; ht++) {
      const u16* vb = &vt[(ht * 16 + l15) * KP];
      bf16x8 b0 = *(const bf16x8*)(vb + koff);
      bf16x8 b1 = *(const bf16x8*)(vb + 32 + koff);
      o[ht] = __builtin_amdgcn_mfma_f32_16x16x32_bf16(ap0, b0, o[ht], 0, 0, 0);
      o[ht] = __builtin_amdgcn_mfma_f32_16x16x32_bf16(ap1, b1, o[ht], 0, 0, 0);
    }
    __syncthreads();
  }

  // ---- write partials (unnormalized O, running m, l)
#pragma unroll
  for (int r = 0; r < 4; r++) {
    int rr = q0 + w * 16 + lh * 4 + r;
    size_t grow = (size_t)b * SEQ + rr;
    float* pob = po + ((size_t)z * NB * SEQ + grow) * 64;
#pragma unroll
    for (int ht = 0; ht < 4; ht++) pob[ht * 16 + l15] = o[ht][r];
    if (l15 == 0) {
      pmp[(size_t)z * NB * SEQ + grow] = mrow[r];
      plp[(size_t)z * NB * SEQ + grow] = lrow[r];
    }
  }
}

// ---------------- merge SPLIT partials -> fp32 out
__global__ __launch_bounds__(256) void merge_k(
    const float* __restrict__ po, const float* __restrict__ pmp,
    const float* __restrict__ plp, float* __restrict__ out) {
  int tid = threadIdx.x;
  int row = blockIdx.x * 32 + (tid >> 3);
  int c8 = (tid & 7) * 8;
  const int RT = NB * SEQ;

  float m[SPLIT], lv[SPLIT];
  float M = -INFINITY;
#pragma unroll
  for (int s = 0; s < SPLIT; s++) {
    m[s] = pmp[(size_t)s * RT + row];
    lv[s] = plp[(size_t)s * RT + row];
    M = fmaxf(M, m[s]);
  }
  float o8[8];
#pragma unroll
  for (int j = 0; j < 8; j++) o8[j] = 0.f;
  float L = 0.f;
  if (M != -INFINITY) {
#pragma unroll
    for (int s = 0; s < SPLIT; s++) {
      float ws = __expf(m[s] - M);
      L += ws * lv[s];
      const float* p = po + ((size_t)s * RT + row) * 64 + c8;
#pragma unroll
      for (int j = 0; j < 8; j++) o8[j] += ws * p[j];
    }
  }
  float inv = (L > 0.f) ? 1.0f / L : 0.f;
  float* op = out + (size_t)row * 64 + c8;
#pragma unroll
  for (int j = 0; j < 8; j++) op[j] = o8[j] * inv;
}

extern "C" void kernel_launch(void* const* d_in, const int* in_sizes, int n_in,
                              void* d_out, int out_size, void* d_ws, size_t ws_size,
                              hipStream_t stream) {
  const float* X   = (const float*)d_in[0];
  const int*   mrk = (const int*)d_in[1];
  const float* Wq  = (const float*)d_in[2];
  const float* Wk  = (const float*)d_in[3];
  const float* Wv  = (const float*)d_in[4];
  const float* Aq  = (const float*)d_in[5];
  const float* Bq  = (const float*)d_in[6];
  const float* Ak  = (const float*)d_in[7];
  const float* Bk  = (const float*)d_in[8];
  const float* Av  = (const float*)d_in[9];
  const float* Bv  = (const float*)d_in[10];

  u16* weff = (u16*)d_ws;
  u16* qws  = (u16*)((char*)d_ws + (512 << 10));
  u16* kws  = qws + (size_t)16384 * 64;
  u16* vws  = kws + (size_t)16384 * 64;
  float* po  = (float*)((char*)d_ws + ((size_t)6656 << 10));
  float* pmp = po + (size_t)SPLIT * 16384 * 64;
  float* plp = pmp + (size_t)SPLIT * 16384;

  fold_k<<<192, 256, 0, stream>>>(Wq, Wk, Wv, Aq, Bq, Ak, Bk, Av, Bv, weff);
  proj_k<<<512, 256, 0, stream>>>(X, weff, qws, kws, vws);
  attn_k<<<dim3(32, 8, SPLIT), 256, 0, stream>>>(qws, kws, vws, mrk, po, pmp, plp);
  merge_k<<<512, 256, 0, stream>>>(po, pmp, plp, (float*)d_out);
}